// Round 18
// baseline (2019.077 us; speedup 1.0000x reference)
//
#include <hip/hip_runtime.h>
#include <hip/hip_bf16.h>

#define N_NODES 65536
#define N_EDGES 393216
#define NB 8
#define HID 128
#define TW 25
#define LAYERS 6
#define BGRAPH 8
#define EPSF 1e-5f
#define TILE_E 128

typedef __attribute__((ext_vector_type(8))) short bf16x8;
typedef __attribute__((ext_vector_type(4))) float f32x4;

// fast swish: x * rcp(1+exp(-x))
__device__ __forceinline__ float swishf(float x) {
    float den = 1.0f + __expf(-x);
    float r;
    asm("v_rcp_f32 %0, %1" : "=v"(r) : "v"(den));
    return x * r;
}

// slow path (prep kernels only)
__device__ __forceinline__ unsigned short f2bf(float x) {
    unsigned int u = __float_as_uint(x);
    u += 0x7fffu + ((u >> 16) & 1u);
    return (unsigned short)(u >> 16);
}

// fast packed f32->bf16 (RNE), gfx950 v_cvt_pk_bf16_f32
__device__ __forceinline__ unsigned int cvtpk2bf(float lo, float hi) {
    unsigned int r;
    asm("v_cvt_pk_bf16_f32 %0, %1, %2" : "=v"(r) : "v"(lo), "v"(hi));
    return r;
}

__device__ __forceinline__ unsigned short f2bf_rne(float x) {
    unsigned int r;
    asm("v_cvt_pk_bf16_f32 %0, %1, %2" : "=v"(r) : "v"(x), "v"(x));
    return (unsigned short)r;
}

__device__ __forceinline__ float bf2f(unsigned short v) {
    return __uint_as_float(((unsigned int)v) << 16);
}

// packed bf16 atomic add (CDNA4): adds 2 bf16 lanes to a 4B-aligned address
__device__ __forceinline__ void atomic_pk_bf16(unsigned short* addr, unsigned int data) {
    asm volatile("global_atomic_pk_add_bf16 %0, %1, off" :: "v"(addr), "v"(data) : "memory");
}

// ---------------------------------------------------------------- gcount
__global__ void gcount_kernel(const int* __restrict__ batch, float* __restrict__ gcount) {
    int b = threadIdx.x;
    if (b >= BGRAPH) return;
    auto lb = [&](int key) {
        int lo = 0, hi = N_NODES;
        while (lo < hi) { int mid = (lo + hi) >> 1; if (batch[mid] < key) lo = mid + 1; else hi = mid; }
        return lo;
    };
    int c = lb(b + 1) - lb(b);
    gcount[b] = c > 0 ? (float)c : 1.0f;
}

// ---------------------------------------------------------------- CSR build
__global__ void count_kernel(const int* __restrict__ ei, int* __restrict__ cnt) {
    int e = blockIdx.x * 256 + threadIdx.x;
    if (e < N_EDGES) atomicAdd(&cnt[ei[N_EDGES + e]], 1);
}

__global__ __launch_bounds__(256) void block_sum_kernel(const int* __restrict__ cnt, int* __restrict__ bsum) {
    __shared__ int s[256];
    int t = threadIdx.x;
    s[t] = cnt[blockIdx.x * 256 + t];
    __syncthreads();
    for (int st = 128; st > 0; st >>= 1) {
        if (t < st) s[t] += s[t + st];
        __syncthreads();
    }
    if (t == 0) bsum[blockIdx.x] = s[0];
}

__global__ __launch_bounds__(256) void scan_bsum_kernel(const int* __restrict__ bsum, int* __restrict__ bpref) {
    __shared__ int s[256];
    int t = threadIdx.x;
    int orig = bsum[t];
    s[t] = orig;
    __syncthreads();
    for (int st = 1; st < 256; st <<= 1) {
        int v = (t >= st) ? s[t - st] : 0;
        __syncthreads();
        s[t] += v;
        __syncthreads();
    }
    bpref[t] = s[t] - orig;
}

__global__ __launch_bounds__(256) void offsets_kernel(const int* __restrict__ cnt, const int* __restrict__ bpref,
                                                      int* __restrict__ cursor) {
    __shared__ int s[256];
    int t = threadIdx.x;
    int base = blockIdx.x * 256;
    int orig = cnt[base + t];
    s[t] = orig;
    __syncthreads();
    for (int st = 1; st < 256; st <<= 1) {
        int v = (t >= st) ? s[t - st] : 0;
        __syncthreads();
        s[t] += v;
        __syncthreads();
    }
    cursor[base + t] = s[t] - orig + bpref[blockIdx.x];
}

__global__ void scatter_kernel(const int* __restrict__ ei, int* __restrict__ cursor,
                               int* __restrict__ src_s, int* __restrict__ dst_s) {
    int e = blockIdx.x * 256 + threadIdx.x;
    if (e >= N_EDGES) return;
    int d = ei[N_EDGES + e];
    int pos = atomicAdd(&cursor[d], 1);
    src_s[pos] = ei[e];
    dst_s[pos] = d;
}

__global__ void invdeg_kernel(const int* __restrict__ cnt, float* __restrict__ inv_deg) {
    int n = blockIdx.x * 256 + threadIdx.x;
    int c = cnt[n];
    inv_deg[n] = 1.0f / (float)(c > 0 ? c : 1);
}

// ---------------------------------------------------------------- weight prep (all bf16, transposed [o][k])
__global__ void w2bf_kernel(const float* __restrict__ m2_w, unsigned short* __restrict__ W2T) {
    int idx = blockIdx.x * 256 + threadIdx.x;   // 6*128*128
    int l = idx >> 14;
    int rem = idx & 16383;
    int n = rem >> 7, k = rem & 127;
    W2T[idx] = f2bf(m2_w[l * 16384 + k * HID + n]);
}

// wAB layout: [l][pass(A=0,B=1)][o=128][k=160]; k<128 = f-part, k>=128 = xin-part
__global__ void w1t_kernel(const float* __restrict__ m1_w, unsigned short* __restrict__ wAB) {
    int idx = blockIdx.x * 256 + threadIdx.x;   // 6*2*128*160 = 245760
    int l = idx / (2 * 128 * 160);
    int rem = idx % (2 * 128 * 160);
    int pass = rem / (128 * 160);
    int o = (rem % (128 * 160)) / 160;
    int k = rem % 160;
    const float* M = m1_w + (size_t)l * 284 * 128;
    float v;
    if (k < 128) {
        v = M[(pass ? 128 + k : k) * 128 + o];
    } else {
        int ku = k - 128;
        if (ku < 25) v = M[(256 + ku) * 128 + o];
        else if (ku == 25) v = M[281 * 128 + o];
        else if (ku == 26) v = M[282 * 128 + o];
        else if (ku == 27) v = M[283 * 128 + o];
        else v = 0.0f;
        if (pass) v = (ku <= 25) ? -v : 0.0f;
    }
    wAB[idx] = f2bf(v);
}

__global__ void u1t_kernel(const float* __restrict__ u1_w, unsigned short* __restrict__ U1T) {
    int idx = blockIdx.x * 256 + threadIdx.x;   // 6*128*256
    int l = idx >> 15;
    int o = (idx >> 8) & 127;
    int k = idx & 255;
    U1T[idx] = f2bf(u1_w[(size_t)l * 258 * 128 + k * 128 + o]);
}

__global__ void u2t_kernel(const float* __restrict__ u2_w, unsigned short* __restrict__ U2T) {
    int idx = blockIdx.x * 256 + threadIdx.x;   // 6*128*128
    int l = idx >> 14;
    int o = (idx >> 7) & 127;
    int k = idx & 127;
    U2T[idx] = f2bf(u2_w[(size_t)l * 16384 + k * 128 + o]);
}

// emb weights: we1T[o][32] (rows 28..31 zero), we2T[o][128]
__global__ void wemb_kernel(const float* __restrict__ ew1, const float* __restrict__ ew2,
                            unsigned short* __restrict__ we1T, unsigned short* __restrict__ we2T) {
    int idx = blockIdx.x * 256 + threadIdx.x;   // 4096 + 16384 = 20480
    if (idx < 4096) {
        int o = idx >> 5, k = idx & 31;
        we1T[idx] = f2bf(k < 28 ? ew1[k * HID + o] : 0.0f);
    } else {
        int j = idx - 4096;
        int o = j >> 7, k = j & 127;
        we2T[j] = f2bf(ew2[k * HID + o]);
    }
}

// xin[n][32] = [u(25), pos/16, t/4, v, 0...] bf16
__global__ void xin_kernel(const float* __restrict__ u, const float* __restrict__ xpos,
                           const float* __restrict__ tpos, const float* __restrict__ vars,
                           unsigned short* __restrict__ xin) {
    int idx = blockIdx.x * 256 + threadIdx.x;   // 65536*32
    int n = idx >> 5, k = idx & 31;
    float v;
    if (k < 25) v = u[n * TW + k];
    else if (k == 25) v = xpos[n] * (1.0f / 16.0f);
    else if (k == 26) v = tpos[n] * 0.25f;
    else if (k == 27) v = vars[n];
    else v = 0.0f;
    xin[idx] = f2bf(v);
}

// ---------------------------------------------------------------- abv chunk: one 32-col group (2 cf), 16 AGPR live
__device__ __forceinline__ void abv_chunk(
    const bf16x8 (&afr)[2][5], int nb, int lr, int lk, int colbase,
    const unsigned short* __restrict__ Wp, const float* __restrict__ b1,
    unsigned short* __restrict__ Op)
{
    f32x4 acc[2][2];
    #pragma unroll
    for (int rt = 0; rt < 2; ++rt)
        #pragma unroll
        for (int cf2 = 0; cf2 < 2; ++cf2)
            acc[rt][cf2] = (f32x4){0.0f, 0.0f, 0.0f, 0.0f};
    #pragma unroll
    for (int cf2 = 0; cf2 < 2; ++cf2) {
        const unsigned short* wrow = Wp + (colbase + cf2 * 16 + lr) * 160 + lk * 8;
        #pragma unroll
        for (int ks = 0; ks < 5; ++ks) {
            bf16x8 bfr = *reinterpret_cast<const bf16x8*>(wrow + ks * 32);
            acc[0][cf2] = __builtin_amdgcn_mfma_f32_16x16x32_bf16(afr[0][ks], bfr, acc[0][cf2], 0, 0, 0);
            acc[1][cf2] = __builtin_amdgcn_mfma_f32_16x16x32_bf16(afr[1][ks], bfr, acc[1][cf2], 0, 0, 0);
        }
    }
    #pragma unroll
    for (int cf2 = 0; cf2 < 2; ++cf2) {
        int col = colbase + cf2 * 16 + lr;
        float bb = b1 ? b1[col] : 0.0f;
        #pragma unroll
        for (int rt = 0; rt < 2; ++rt) {
            #pragma unroll
            for (int j = 0; j < 4; ++j) {
                int row = nb + rt * 16 + lk * 4 + j;
                Op[(size_t)row * HID + col] = f2bf_rne(acc[rt][cf2][j] + bb);
            }
        }
    }
}

// ---------------------------------------------------------------- fused emb + layer-0 abv (all MFMA; per-wave 32 rows)
__global__ __launch_bounds__(256) void emb_abv_kernel(
    const unsigned short* __restrict__ xin_bf,
    const unsigned short* __restrict__ we1T, const float* __restrict__ eb1,
    const unsigned short* __restrict__ we2T, const float* __restrict__ eb2,
    const unsigned short* __restrict__ wA, const unsigned short* __restrict__ wB,
    const float* __restrict__ b1,
    unsigned short* __restrict__ f_bf,
    unsigned short* __restrict__ A_bf, unsigned short* __restrict__ Bv_bf)
{
    __shared__ unsigned short q_lds[4 * 32 * HID];   // 32 KB, per-wave 8 KB regions
    const int tid = threadIdx.x;
    const int w = tid >> 6, l = tid & 63;
    const int lr = l & 15, lk = l >> 4;
    const int nb = blockIdx.x * 128 + w * 32;
    char* qbase = reinterpret_cast<char*>(q_lds) + w * 8192;

    bf16x8 xfr[2];
    #pragma unroll
    for (int rt = 0; rt < 2; ++rt)
        xfr[rt] = *reinterpret_cast<const bf16x8*>(xin_bf + (size_t)(nb + rt * 16 + lr) * 32 + lk * 8);

    // GEMM1 (K=32) chunked
    #pragma unroll 1
    for (int cc = 0; cc < 4; ++cc) {
        f32x4 acc1[2][2];
        #pragma unroll
        for (int rt = 0; rt < 2; ++rt)
            #pragma unroll
            for (int cf2 = 0; cf2 < 2; ++cf2)
                acc1[rt][cf2] = (f32x4){0.0f, 0.0f, 0.0f, 0.0f};
        #pragma unroll
        for (int cf2 = 0; cf2 < 2; ++cf2) {
            bf16x8 bfr = *reinterpret_cast<const bf16x8*>(we1T + ((cc * 2 + cf2) * 16 + lr) * 32 + lk * 8);
            acc1[0][cf2] = __builtin_amdgcn_mfma_f32_16x16x32_bf16(xfr[0], bfr, acc1[0][cf2], 0, 0, 0);
            acc1[1][cf2] = __builtin_amdgcn_mfma_f32_16x16x32_bf16(xfr[1], bfr, acc1[1][cf2], 0, 0, 0);
        }
        #pragma unroll
        for (int cf2 = 0; cf2 < 2; ++cf2) {
            int col = (cc * 2 + cf2) * 16 + lr;
            float bb = eb1[col];
            #pragma unroll
            for (int rt = 0; rt < 2; ++rt)
                #pragma unroll
                for (int j = 0; j < 4; ++j) {
                    float qv = swishf(acc1[rt][cf2][j] + bb);
                    int rloc = rt * 16 + lk * 4 + j;
                    *reinterpret_cast<unsigned short*>(qbase + rloc * 256 + ((col * 2) ^ ((rloc & 7) << 4))) = f2bf_rne(qv);
                }
        }
    }

    // GEMM2 (K=128) chunked; f kept in second LDS region
    __shared__ unsigned short f_lds2[4 * 32 * HID];
    char* fbase = reinterpret_cast<char*>(f_lds2) + w * 8192;
    #pragma unroll 1
    for (int cc = 0; cc < 4; ++cc) {
        f32x4 acc2[2][2];
        #pragma unroll
        for (int rt = 0; rt < 2; ++rt)
            #pragma unroll
            for (int cf2 = 0; cf2 < 2; ++cf2)
                acc2[rt][cf2] = (f32x4){0.0f, 0.0f, 0.0f, 0.0f};
        #pragma unroll
        for (int ks = 0; ks < 4; ++ks) {
            bf16x8 afrq[2];
            #pragma unroll
            for (int rt = 0; rt < 2; ++rt) {
                int rloc = rt * 16 + lr;
                afrq[rt] = *reinterpret_cast<const bf16x8*>(qbase + rloc * 256 + ((ks * 64 + lk * 16) ^ ((rloc & 7) << 4)));
            }
            #pragma unroll
            for (int cf2 = 0; cf2 < 2; ++cf2) {
                bf16x8 bfr = *reinterpret_cast<const bf16x8*>(we2T + ((cc * 2 + cf2) * 16 + lr) * HID + ks * 32 + lk * 8);
                acc2[0][cf2] = __builtin_amdgcn_mfma_f32_16x16x32_bf16(afrq[0], bfr, acc2[0][cf2], 0, 0, 0);
                acc2[1][cf2] = __builtin_amdgcn_mfma_f32_16x16x32_bf16(afrq[1], bfr, acc2[1][cf2], 0, 0, 0);
            }
        }
        #pragma unroll
        for (int cf2 = 0; cf2 < 2; ++cf2) {
            int col = (cc * 2 + cf2) * 16 + lr;
            float bb = eb2[col];
            #pragma unroll
            for (int rt = 0; rt < 2; ++rt)
                #pragma unroll
                for (int j = 0; j < 4; ++j) {
                    float fv = swishf(acc2[rt][cf2][j] + bb);
                    unsigned short fb = f2bf_rne(fv);
                    int rloc = rt * 16 + lk * 4 + j;
                    f_bf[(size_t)(nb + rloc) * HID + col] = fb;
                    *reinterpret_cast<unsigned short*>(fbase + rloc * 256 + ((col * 2) ^ ((rloc & 7) << 4))) = fb;
                }
        }
    }

    bf16x8 afr[2][5];
    #pragma unroll
    for (int rt = 0; rt < 2; ++rt) {
        int rloc = rt * 16 + lr;
        #pragma unroll
        for (int ks = 0; ks < 4; ++ks)
            afr[rt][ks] = *reinterpret_cast<const bf16x8*>(fbase + rloc * 256 + ((ks * 64 + lk * 16) ^ ((rloc & 7) << 4)));
        afr[rt][4] = xfr[rt];
    }
    #pragma unroll 1
    for (int cc = 0; cc < 4; ++cc) abv_chunk(afr, nb, lr, lk, cc * 32, wA, b1, A_bf);
    #pragma unroll 1
    for (int cc = 0; cc < 4; ++cc) abv_chunk(afr, nb, lr, lk, cc * 32, wB, nullptr, Bv_bf);
}

// ---------------------------------------------------------------- fused norm + next-layer abv — col-split block (32 rows, grid 2048)
__global__ __launch_bounds__(256) void norm_abv_kernel(
    const unsigned short* __restrict__ h, const int* __restrict__ batch,
    const float* __restrict__ dsum, const float* __restrict__ dsq,
    const float* __restrict__ gcount,
    const unsigned short* __restrict__ xin_bf,
    const unsigned short* __restrict__ wA, const unsigned short* __restrict__ wB,
    const float* __restrict__ b1,
    unsigned short* __restrict__ f_bf,
    unsigned short* __restrict__ A_bf, unsigned short* __restrict__ Bv_bf)
{
    __shared__ unsigned short f_lds[32 * HID];   // 8 KB, shared across waves
    const int tid = threadIdx.x;
    const int w = tid >> 6, l = tid & 63;
    const int lr = l & 15, lk = l >> 4;
    const int nb = blockIdx.x * 32;

    // phase 1: wave w normalizes k-slice ks=w (cols w*32 + lk*8 .. +8) for all 32 rows
    {
        const int ks = w;
        const int c0 = ks * 32 + lk * 8;
        #pragma unroll
        for (int rt = 0; rt < 2; ++rt) {
            int row = nb + rt * 16 + lr;
            int b = batch[row];
            float inv = 1.0f / gcount[b];
            uint4 hv4 = *reinterpret_cast<const uint4*>(h + (size_t)row * HID + c0);
            unsigned int hw[4] = {hv4.x, hv4.y, hv4.z, hv4.w};
            float4 s0 = *reinterpret_cast<const float4*>(dsum + b * HID + c0);
            float4 s1 = *reinterpret_cast<const float4*>(dsum + b * HID + c0 + 4);
            float4 q0 = *reinterpret_cast<const float4*>(dsq + b * HID + c0);
            float4 q1 = *reinterpret_cast<const float4*>(dsq + b * HID + c0 + 4);
            float o[8];
            #pragma unroll
            for (int i = 0; i < 8; ++i) {
                float hx = (i & 1) ? __uint_as_float(hw[i >> 1] & 0xffff0000u)
                                   : __uint_as_float(hw[i >> 1] << 16);
                float sm = (i < 4) ? reinterpret_cast<const float*>(&s0)[i] : reinterpret_cast<const float*>(&s1)[i - 4];
                float sq = (i < 4) ? reinterpret_cast<const float*>(&q0)[i] : reinterpret_cast<const float*>(&q1)[i - 4];
                float mean = sm * inv;
                float var = sq * inv - mean * mean;
                o[i] = (hx - mean) * rsqrtf(var + EPSF);
            }
            uint4 t;
            t.x = cvtpk2bf(o[0], o[1]);
            t.y = cvtpk2bf(o[2], o[3]);
            t.z = cvtpk2bf(o[4], o[5]);
            t.w = cvtpk2bf(o[6], o[7]);
            *reinterpret_cast<uint4*>(f_bf + (size_t)row * HID + c0) = t;
            int rloc = rt * 16 + lr;
            *reinterpret_cast<uint4*>(reinterpret_cast<char*>(f_lds) + rloc * 256 + ((c0 * 2) ^ ((rloc & 7) << 4))) = t;
        }
    }
    __syncthreads();

    // phase 2: each wave computes its 32-col chunk of A and Bv
    bf16x8 afr[2][5];
    #pragma unroll
    for (int rt = 0; rt < 2; ++rt) {
        int rloc = rt * 16 + lr;
        #pragma unroll
        for (int ks = 0; ks < 4; ++ks)
            afr[rt][ks] = *reinterpret_cast<const bf16x8*>(
                reinterpret_cast<const char*>(f_lds) + rloc * 256 + ((ks * 64 + lk * 16) ^ ((rloc & 7) << 4)));
        afr[rt][4] = *reinterpret_cast<const bf16x8*>(xin_bf + (size_t)(nb + rt * 16 + lr) * 32 + lk * 8);
    }
    abv_chunk(afr, nb, lr, lk, w * 32, wA, b1, A_bf);
    abv_chunk(afr, nb, lr, lk, w * 32, wB, nullptr, Bv_bf);
}

// ---------------------------------------------------------------- fused edge kernel: direct fragment gather, chunked,
// mean folded via inv_deg, bf16 packed atomics into agg_bf
__global__ __launch_bounds__(256) void edge_mfma_kernel(
    const int* __restrict__ src_s, const int* __restrict__ dst_s,
    const float* __restrict__ inv_deg,
    const unsigned short* __restrict__ A_bf, const unsigned short* __restrict__ Bv_bf,
    const unsigned short* __restrict__ W2T, const float* __restrict__ b2,
    unsigned short* __restrict__ agg_bf)
{
    const int tid = threadIdx.x;
    const int w = tid >> 6, l = tid & 63;
    const int lr = l & 15, lk = l >> 4;
    const int e0 = blockIdx.x * TILE_E + w * 32;

    bf16x8 afr[2][4];
    #pragma unroll
    for (int rt = 0; rt < 2; ++rt) {
        int e = e0 + ((lr >> 2) << 3) + rt * 4 + (lr & 3);
        int dn = dst_s[e], sn = src_s[e];
        const unsigned short* ap = A_bf + (size_t)dn * HID + lk * 8;
        const unsigned short* bp = Bv_bf + (size_t)sn * HID + lk * 8;
        #pragma unroll
        for (int ks = 0; ks < 4; ++ks) {
            uint4 av = *reinterpret_cast<const uint4*>(ap + ks * 32);
            uint4 bv = *reinterpret_cast<const uint4*>(bp + ks * 32);
            auto proc = [](unsigned int aw, unsigned int bw) -> unsigned int {
                float a0 = __uint_as_float(aw << 16), a1 = __uint_as_float(aw & 0xffff0000u);
                float b0 = __uint_as_float(bw << 16), b1 = __uint_as_float(bw & 0xffff0000u);
                return cvtpk2bf(swishf(a0 + b0), swishf(a1 + b1));
            };
            union { bf16x8 v; unsigned int u[4]; } t;
            t.u[0] = proc(av.x, bv.x);
            t.u[1] = proc(av.y, bv.y);
            t.u[2] = proc(av.z, bv.z);
            t.u[3] = proc(av.w, bv.w);
            afr[rt][ks] = t.v;
        }
    }

    const int ebase = e0 + lk * 8;
    int4 dA4 = *reinterpret_cast<const int4*>(dst_s + ebase);
    int4 dB4 = *reinterpret_cast<const int4*>(dst_s + ebase + 4);
    int d[8] = {dA4.x, dA4.y, dA4.z, dA4.w, dB4.x, dB4.y, dB4.z, dB4.w};
    bool sm[7];
    int roff[8];
    float ivd8[8];
    #pragma unroll
    for (int m = 0; m < 7; ++m) sm[m] = (d[m + 1] == d[m]);
    #pragma unroll
    for (int m = 0; m < 8; ++m) roff[m] = d[m] * HID;
    #pragma unroll
    for (int m = 0; m < 8; ++m) ivd8[m] = inv_deg[d[m]];

    #pragma unroll 1
    for (int cc = 0; cc < 4; ++cc) {
        f32x4 acc[2][2];
        #pragma unroll
        for (int rt = 0; rt < 2; ++rt)
            #pragma unroll
            for (int cf2 = 0; cf2 < 2; ++cf2)
                acc[rt][cf2] = (f32x4){0.0f, 0.0f, 0.0f, 0.0f};
        #pragma unroll
        for (int cf2 = 0; cf2 < 2; ++cf2) {
            const unsigned short* wrow = W2T + ((cc * 2 + cf2) * 16 + lr) * HID + lk * 8;
            #pragma unroll
            for (int ks = 0; ks < 4; ++ks) {
                bf16x8 bfr = *reinterpret_cast<const bf16x8*>(wrow + ks * 32);
                acc[0][cf2] = __builtin_amdgcn_mfma_f32_16x16x32_bf16(afr[0][ks], bfr, acc[0][cf2], 0, 0, 0);
                acc[1][cf2] = __builtin_amdgcn_mfma_f32_16x16x32_bf16(afr[1][ks], bfr, acc[1][cf2], 0, 0, 0);
            }
        }
        #pragma unroll
        for (int cf2 = 0; cf2 < 2; ++cf2) {
            int col = (cc * 2 + cf2) * 16 + lr;
            float bias = b2[col];
            int colb = col & ~1;
            bool hi = (col & 1) != 0;
            float v[8];
            #pragma unroll
            for (int m = 0; m < 8; ++m) v[m] = swishf(acc[m >> 2][cf2][m & 3] + bias);
            float run = v[0];
            #pragma unroll
            for (int m = 1; m < 8; ++m) {
                if (sm[m - 1]) run += v[m];
                else {
                    float x = run * ivd8[m - 1];
                    unsigned int pk = cvtpk2bf(hi ? 0.0f : x, hi ? x : 0.0f);
                    atomic_pk_bf16(agg_bf + (size_t)roff[m - 1] + colb, pk);
                    run = v[m];
                }
            }
            float x = run * ivd8[7];
            unsigned int pk = cvtpk2bf(hi ? 0.0f : x, hi ? x : 0.0f);
            atomic_pk_bf16(agg_bf + (size_t)roff[7] + colb, pk);
        }
    }
}

// ---------------------------------------------------------------- update — col-split block (32 rows, grid 2048)
// agg is bf16 with 1/deg pre-folded; block zeroes its agg rows after GEMM1 (removes per-layer memset)
__global__ __launch_bounds__(256) void update_mfma_kernel(
    const unsigned short* __restrict__ f_bf, unsigned short* __restrict__ agg_bf,
    const float* __restrict__ tpos, const float* __restrict__ vars,
    const int* __restrict__ batch,
    const unsigned short* __restrict__ U1T, const float* __restrict__ u1tv,
    const float* __restrict__ b1, const unsigned short* __restrict__ U2T,
    const float* __restrict__ b2, unsigned short* __restrict__ h,
    float* __restrict__ dsum, float* __restrict__ dsq)
{
    __shared__ unsigned short q_lds[32 * HID];   // 8 KB, shared across waves
    const int tid = threadIdx.x;
    const int w = tid >> 6, l = tid & 63;
    const int lr = l & 15, lk = l >> 4;
    const int nb = blockIdx.x * 32;

    float tn[2][4], vn[2][4];
    #pragma unroll
    for (int rt = 0; rt < 2; ++rt)
        #pragma unroll
        for (int j = 0; j < 4; ++j) {
            int row = nb + rt * 16 + lk * 4 + j;
            tn[rt][j] = tpos[row] * 0.25f;
            vn[rt][j] = vars[row];
        }

    // GEMM1 (K=256): wave w computes cols w*32..+31; agg fragments read directly as bf16
    {
        f32x4 acc[2][2];
        #pragma unroll
        for (int rt = 0; rt < 2; ++rt)
            #pragma unroll
            for (int cf2 = 0; cf2 < 2; ++cf2)
                acc[rt][cf2] = (f32x4){0.0f, 0.0f, 0.0f, 0.0f};
        #pragma unroll
        for (int ks = 0; ks < 8; ++ks) {
            bf16x8 afr[2];
            #pragma unroll
            for (int rt = 0; rt < 2; ++rt) {
                int row = nb + rt * 16 + lr;
                const unsigned short* base = (ks < 4) ? f_bf : agg_bf;
                afr[rt] = *reinterpret_cast<const bf16x8*>(base + (size_t)row * HID + (ks & 3) * 32 + lk * 8);
            }
            #pragma unroll
            for (int cf2 = 0; cf2 < 2; ++cf2) {
                bf16x8 bfr = *reinterpret_cast<const bf16x8*>(U1T + ((w * 2 + cf2) * 16 + lr) * 256 + ks * 32 + lk * 8);
                acc[0][cf2] = __builtin_amdgcn_mfma_f32_16x16x32_bf16(afr[0], bfr, acc[0][cf2], 0, 0, 0);
                acc[1][cf2] = __builtin_amdgcn_mfma_f32_16x16x32_bf16(afr[1], bfr, acc[1][cf2], 0, 0, 0);
            }
        }
        // epilogue 1: tv + bias + swish -> shared q_lds (swizzled)
        #pragma unroll
        for (int cf2 = 0; cf2 < 2; ++cf2) {
            int col = w * 32 + cf2 * 16 + lr;
            float bb = b1[col], wt = u1tv[col], wv = u1tv[HID + col];
            #pragma unroll
            for (int rt = 0; rt < 2; ++rt)
                #pragma unroll
                for (int j = 0; j < 4; ++j) {
                    float qv = swishf(acc[rt][cf2][j] + bb + tn[rt][j] * wt + vn[rt][j] * wv);
                    int rloc = rt * 16 + lk * 4 + j;
                    *reinterpret_cast<unsigned short*>(reinterpret_cast<char*>(q_lds) + rloc * 256 + ((col * 2) ^ ((rloc & 7) << 4))) = f2bf_rne(qv);
                }
        }
    }
    __syncthreads();

    // zero own agg rows for next layer's edge accumulation (replaces per-layer memset)
    {
        uint4 z = {0u, 0u, 0u, 0u};
        #pragma unroll
        for (int i = 0; i < 2; ++i) {
            int q = tid + i * 256;
            int r = q >> 4, cb = q & 15;
            *reinterpret_cast<uint4*>(agg_bf + (size_t)(nb + r) * HID + cb * 8) = z;
        }
    }

    // GEMM2 (K=128): wave w computes cols w*32..+31
    const int bfirst = batch[nb];
    const bool uni = (bfirst == batch[nb + 31]);
    {
        f32x4 acc2[2][2];
        #pragma unroll
        for (int rt = 0; rt < 2; ++rt)
            #pragma unroll
            for (int cf2 = 0; cf2 < 2; ++cf2)
                acc2[rt][cf2] = (f32x4){0.0f, 0.0f, 0.0f, 0.0f};
        #pragma unroll
        for (int ks = 0; ks < 4; ++ks) {
            bf16x8 afr[2];
            #pragma unroll
            for (int rt = 0; rt < 2; ++rt) {
                int rloc = rt * 16 + lr;
                afr[rt] = *reinterpret_cast<const bf16x8*>(
                    reinterpret_cast<const char*>(q_lds) + rloc * 256 + ((ks * 64 + lk * 16) ^ ((rloc & 7) << 4)));
            }
            #pragma unroll
            for (int cf2 = 0; cf2 < 2; ++cf2) {
                bf16x8 bfr = *reinterpret_cast<const bf16x8*>(U2T + ((w * 2 + cf2) * 16 + lr) * HID + ks * 32 + lk * 8);
                acc2[0][cf2] = __builtin_amdgcn_mfma_f32_16x16x32_bf16(afr[0], bfr, acc2[0][cf2], 0, 0, 0);
                acc2[1][cf2] = __builtin_amdgcn_mfma_f32_16x16x32_bf16(afr[1], bfr, acc2[1][cf2], 0, 0, 0);
            }
        }
        // epilogue 2: residual + h write + stats
        #pragma unroll
        for (int cf2 = 0; cf2 < 2; ++cf2) {
            int col = w * 32 + cf2 * 16 + lr;
            float bb = b2[col];
            float s = 0.0f, s2 = 0.0f;
            #pragma unroll
            for (int rt = 0; rt < 2; ++rt)
                #pragma unroll
                for (int j = 0; j < 4; ++j) {
                    int row = nb + rt * 16 + lk * 4 + j;
                    float fres = bf2f(f_bf[(size_t)row * HID + col]);
                    float hv = fres + swishf(acc2[rt][cf2][j] + bb);
                    unsigned short hb = f2bf_rne(hv);
                    h[(size_t)row * HID + col] = hb;
                    float hvr = bf2f(hb);
                    if (uni) { s += hvr; s2 += hvr * hvr; }
                    else {
                        int b = batch[row];
                        atomicAdd(&dsum[b * HID + col], hvr);
                        atomicAdd(&dsq[b * HID + col], hvr * hvr);
                    }
                }
            if (uni) {
                s += __shfl_xor(s, 16); s += __shfl_xor(s, 32);
                s2 += __shfl_xor(s2, 16); s2 += __shfl_xor(s2, 32);
                if (lk == 0) {
                    atomicAdd(&dsum[bfirst * HID + col], s);
                    atomicAdd(&dsq[bfirst * HID + col], s2);
                }
            }
        }
    }
}

// ---------------------------------------------------------------- conv head with fused final instance-norm
__global__ __launch_bounds__(256) void head_kernel(
    const unsigned short* __restrict__ h, const int* __restrict__ batch,
    const float* __restrict__ dsum, const float* __restrict__ dsq,
    const float* __restrict__ gcount,
    const float* __restrict__ u,
    const float* __restrict__ c1w, const float* __restrict__ c1b,
    const float* __restrict__ c2w, const float* __restrict__ c2b,
    float* __restrict__ out)
{
    __shared__ float fs[16][HID];
    __shared__ float y1[16][8][40];
    const int tid = threadIdx.x;
    const int n0 = blockIdx.x * 16;
    {
        int node = tid >> 4, cb = tid & 15;
        int n = n0 + node;
        int b = batch[n];
        float inv = 1.0f / gcount[b];
        int c0 = cb * 8;
        uint4 v = *reinterpret_cast<const uint4*>(h + (size_t)n * HID + c0);
        unsigned int wv[4] = {v.x, v.y, v.z, v.w};
        #pragma unroll
        for (int i = 0; i < 8; ++i) {
            float hx = (i & 1) ? __uint_as_float(wv[i >> 1] & 0xffff0000u)
                               : __uint_as_float(wv[i >> 1] << 16);
            float mean = dsum[b * HID + c0 + i] * inv;
            float var = dsq[b * HID + c0 + i] * inv - mean * mean;
            fs[node][c0 + i] = (hx - mean) * rsqrtf(var + EPSF);
        }
    }
    __syncthreads();
    {
        const int node = tid >> 4;
        const int rem = tid & 15;
        const int o = rem >> 1;
        const int ph = rem & 1;
        const float cb = c1b[o];
        float wk[16];
        #pragma unroll
        for (int k = 0; k < 16; ++k) wk[k] = c1w[o * 16 + k];
        for (int p = ph * 19; p < ph * 19 + 19; ++p) {
            float acc = cb;
            #pragma unroll
            for (int k = 0; k < 16; ++k) acc += fs[node][p * 3 + k] * wk[k];
            y1[node][o][p] = swishf(acc);
        }
    }
    __syncthreads();
    const float cb2 = c2b[0];
    #pragma unroll
    for (int pass = 0; pass < 2; ++pass) {
        int unit = tid + pass * 256;
        if (unit < 16 * TW) {
            int node = unit / TW, t = unit % TW;
            float acc = cb2;
            #pragma unroll
            for (int o = 0; o < 8; ++o)
                #pragma unroll
                for (int k = 0; k < 14; ++k)
                    acc += y1[node][o][t + k] * c2w[o * 14 + k];
            int n = n0 + node;
            out[n * TW + t] = u[n * TW + (TW - 1)] + (0.016f * (float)(t + 1)) * acc;
        }
    }
}

// ---------------------------------------------------------------- launch
extern "C" void kernel_launch(void* const* d_in, const int* in_sizes, int n_in,
                              void* d_out, int out_size, void* d_ws, size_t ws_size,
                              hipStream_t stream)
{
    (void)in_sizes; (void)n_in; (void)out_size; (void)ws_size;
    const float* u      = (const float*)d_in[0];
    const float* xpos   = (const float*)d_in[1];
    const float* tpos   = (const float*)d_in[2];
    const float* vars   = (const float*)d_in[3];
    const int*   ei     = (const int*)d_in[4];
    const int*   batch  = (const int*)d_in[5];
    const float* emb_w1 = (const float*)d_in[6];
    const float* emb_b1 = (const float*)d_in[7];
    const float* emb_w2 = (const float*)d_in[8];
    const float* emb_b2 = (const float*)d_in[9];
    const float* m1_w   = (const float*)d_in[10];
    const float* m1_b   = (const float*)d_in[11];
    const float* m2_w   = (const float*)d_in[12];
    const float* m2_b   = (const float*)d_in[13];
    const float* u1_w   = (const float*)d_in[14];
    const float* u1_b   = (const float*)d_in[15];
    const float* u2_w   = (const float*)d_in[16];
    const float* u2_b   = (const float*)d_in[17];
    const float* c1w    = (const float*)d_in[18];
    const float* c1b    = (const float*)d_in[19];
    const float* c2w    = (const float*)d_in[20];
    const float* c2b    = (const float*)d_in[21];
    float* out = (float*)d_out;

    char* ws = (char*)d_ws;
    char*  p      = ws;
    unsigned short* agg_bf = (unsigned short*)p;  p += (size_t)N_NODES * HID * 2;
    unsigned short* h_bf   = (unsigned short*)p;  p += (size_t)N_NODES * HID * 2;
    unsigned short* A_bf   = (unsigned short*)p;  p += (size_t)N_NODES * HID * 2;
    unsigned short* Bv_bf  = (unsigned short*)p;  p += (size_t)N_NODES * HID * 2;
    unsigned short* f_bf   = (unsigned short*)p;  p += (size_t)N_NODES * HID * 2;
    unsigned short* xin_bf = (unsigned short*)p;  p += (size_t)N_NODES * 32 * 2;
    int* cnt      = (int*)p;               p += (size_t)N_NODES * 4;
    int* cursor   = (int*)p;               p += (size_t)N_NODES * 4;
    float* inv_deg = (float*)p;            p += (size_t)N_NODES * 4;
    int* src_s    = (int*)p;               p += (size_t)N_EDGES * 4;
    int* dst_s    = (int*)p;               p += (size_t)N_EDGES * 4;
    int* bsum     = (int*)p;               p += 256 * 4;
    int* bpref    = (int*)p;               p += 256 * 4;
    float* dsumL  = (float*)p;             p += (size_t)LAYERS * BGRAPH * HID * 4;
    float* dsqL   = (float*)p;             p += (size_t)LAYERS * BGRAPH * HID * 4;
    float* gcount = (float*)p;             p += BGRAPH * 4;
    unsigned short* W2T  = (unsigned short*)p;  p += (size_t)LAYERS * HID * HID * 2;
    unsigned short* wAB  = (unsigned short*)p;  p += (size_t)LAYERS * 2 * 128 * 160 * 2;
    unsigned short* U1T  = (unsigned short*)p;  p += (size_t)LAYERS * 128 * 256 * 2;
    unsigned short* U2T  = (unsigned short*)p;  p += (size_t)LAYERS * 128 * 128 * 2;
    unsigned short* we1T = (unsigned short*)p;  p += 128 * 32 * 2;
    unsigned short* we2T = (unsigned short*)p;  p += 128 * 128 * 2;

    // CSR build
    hipMemsetAsync(cnt, 0, (size_t)N_NODES * 4, stream);
    count_kernel<<<N_EDGES / 256, 256, 0, stream>>>(ei, cnt);
    block_sum_kernel<<<N_NODES / 256, 256, 0, stream>>>(cnt, bsum);
    scan_bsum_kernel<<<1, 256, 0, stream>>>(bsum, bpref);
    offsets_kernel<<<N_NODES / 256, 256, 0, stream>>>(cnt, bpref, cursor);
    scatter_kernel<<<N_EDGES / 256, 256, 0, stream>>>(ei, cursor, src_s, dst_s);
    invdeg_kernel<<<N_NODES / 256, 256, 0, stream>>>(cnt, inv_deg);

    // weight / input prep
    w2bf_kernel<<<LAYERS * HID * HID / 256, 256, 0, stream>>>(m2_w, W2T);
    w1t_kernel<<<LAYERS * 2 * 128 * 160 / 256, 256, 0, stream>>>(m1_w, wAB);
    u1t_kernel<<<LAYERS * 128 * 256 / 256, 256, 0, stream>>>(u1_w, U1T);
    u2t_kernel<<<LAYERS * 128 * 128 / 256, 256, 0, stream>>>(u2_w, U2T);
    wemb_kernel<<<80, 256, 0, stream>>>(emb_w1, emb_w2, we1T, we2T);
    xin_kernel<<<N_NODES * 32 / 256, 256, 0, stream>>>(u, xpos, tpos, vars, xin_bf);
    gcount_kernel<<<1, 64, 0, stream>>>(batch, gcount);
    hipMemsetAsync(dsumL, 0, (size_t)2 * LAYERS * BGRAPH * HID * 4, stream);
    hipMemsetAsync(agg_bf, 0, (size_t)N_NODES * HID * 2, stream);   // once; updates re-zero per layer

    // fused emb + layer-0 abv
    emb_abv_kernel<<<N_NODES / 128, 256, 0, stream>>>(
        xin_bf, we1T, emb_b1, we2T, emb_b2,
        wAB, wAB + 128 * 160, m1_b, f_bf, A_bf, Bv_bf);

    for (int l = 0; l < LAYERS; ++l) {
        edge_mfma_kernel<<<N_EDGES / TILE_E, 256, 0, stream>>>(
            src_s, dst_s, inv_deg, A_bf, Bv_bf, W2T + (size_t)l * HID * HID,
            m2_b + (size_t)l * HID, agg_bf);
        update_mfma_kernel<<<N_NODES / 32, 256, 0, stream>>>(
            f_bf, agg_bf, tpos, vars, batch,
            U1T + (size_t)l * 128 * 256,
            u1_w + (size_t)l * 258 * 128 + 256 * 128,
            u1_b + (size_t)l * HID,
            U2T + (size_t)l * 128 * 128,
            u2_b + (size_t)l * HID, h_bf,
            dsumL + (size_t)l * BGRAPH * HID, dsqL + (size_t)l * BGRAPH * HID);
        if (l < LAYERS - 1) {
            norm_abv_kernel<<<N_NODES / 32, 256, 0, stream>>>(
                h_bf, batch, dsumL + (size_t)l * BGRAPH * HID, dsqL + (size_t)l * BGRAPH * HID,
                gcount, xin_bf,
                wAB + (size_t)(l + 1) * 2 * 128 * 160,
                wAB + (size_t)(l + 1) * 2 * 128 * 160 + 128 * 160,
                m1_b + (size_t)(l + 1) * HID,
                f_bf, A_bf, Bv_bf);
        }
    }
    head_kernel<<<N_NODES / 16, 256, 0, stream>>>(
        h_bf, batch, dsumL + (size_t)(LAYERS - 1) * BGRAPH * HID,
        dsqL + (size_t)(LAYERS - 1) * BGRAPH * HID, gcount,
        u, c1w, c1b, c2w, c2b, out);
}

// Round 19
// 1142.034 us; speedup vs baseline: 1.7680x; 1.7680x over previous
//
#include <hip/hip_runtime.h>
#include <hip/hip_bf16.h>

#define N_NODES 65536
#define N_EDGES 393216
#define NB 8
#define HID 128
#define TW 25
#define LAYERS 6
#define BGRAPH 8
#define EPSF 1e-5f
#define TILE_E 128

typedef __attribute__((ext_vector_type(8))) short bf16x8;
typedef __attribute__((ext_vector_type(4))) float f32x4;

// fast swish: x * rcp(1+exp(-x))
__device__ __forceinline__ float swishf(float x) {
    float den = 1.0f + __expf(-x);
    float r;
    asm("v_rcp_f32 %0, %1" : "=v"(r) : "v"(den));
    return x * r;
}

// slow path (prep kernels only)
__device__ __forceinline__ unsigned short f2bf(float x) {
    unsigned int u = __float_as_uint(x);
    u += 0x7fffu + ((u >> 16) & 1u);
    return (unsigned short)(u >> 16);
}

// fast packed f32->bf16 (RNE), gfx950 v_cvt_pk_bf16_f32
__device__ __forceinline__ unsigned int cvtpk2bf(float lo, float hi) {
    unsigned int r;
    asm("v_cvt_pk_bf16_f32 %0, %1, %2" : "=v"(r) : "v"(lo), "v"(hi));
    return r;
}

__device__ __forceinline__ unsigned short f2bf_rne(float x) {
    unsigned int r;
    asm("v_cvt_pk_bf16_f32 %0, %1, %2" : "=v"(r) : "v"(x), "v"(x));
    return (unsigned short)r;
}

__device__ __forceinline__ float bf2f(unsigned short v) {
    return __uint_as_float(((unsigned int)v) << 16);
}

// ---------------------------------------------------------------- gcount
__global__ void gcount_kernel(const int* __restrict__ batch, float* __restrict__ gcount) {
    int b = threadIdx.x;
    if (b >= BGRAPH) return;
    auto lb = [&](int key) {
        int lo = 0, hi = N_NODES;
        while (lo < hi) { int mid = (lo + hi) >> 1; if (batch[mid] < key) lo = mid + 1; else hi = mid; }
        return lo;
    };
    int c = lb(b + 1) - lb(b);
    gcount[b] = c > 0 ? (float)c : 1.0f;
}

// ---------------------------------------------------------------- CSR build
__global__ void count_kernel(const int* __restrict__ ei, int* __restrict__ cnt) {
    int e = blockIdx.x * 256 + threadIdx.x;
    if (e < N_EDGES) atomicAdd(&cnt[ei[N_EDGES + e]], 1);
}

__global__ __launch_bounds__(256) void block_sum_kernel(const int* __restrict__ cnt, int* __restrict__ bsum) {
    __shared__ int s[256];
    int t = threadIdx.x;
    s[t] = cnt[blockIdx.x * 256 + t];
    __syncthreads();
    for (int st = 128; st > 0; st >>= 1) {
        if (t < st) s[t] += s[t + st];
        __syncthreads();
    }
    if (t == 0) bsum[blockIdx.x] = s[0];
}

__global__ __launch_bounds__(256) void scan_bsum_kernel(const int* __restrict__ bsum, int* __restrict__ bpref) {
    __shared__ int s[256];
    int t = threadIdx.x;
    int orig = bsum[t];
    s[t] = orig;
    __syncthreads();
    for (int st = 1; st < 256; st <<= 1) {
        int v = (t >= st) ? s[t - st] : 0;
        __syncthreads();
        s[t] += v;
        __syncthreads();
    }
    bpref[t] = s[t] - orig;
}

__global__ __launch_bounds__(256) void offsets_kernel(const int* __restrict__ cnt, const int* __restrict__ bpref,
                                                      int* __restrict__ cursor) {
    __shared__ int s[256];
    int t = threadIdx.x;
    int base = blockIdx.x * 256;
    int orig = cnt[base + t];
    s[t] = orig;
    __syncthreads();
    for (int st = 1; st < 256; st <<= 1) {
        int v = (t >= st) ? s[t - st] : 0;
        __syncthreads();
        s[t] += v;
        __syncthreads();
    }
    cursor[base + t] = s[t] - orig + bpref[blockIdx.x];
}

__global__ void scatter_kernel(const int* __restrict__ ei, int* __restrict__ cursor,
                               int* __restrict__ src_s, int* __restrict__ dst_s) {
    int e = blockIdx.x * 256 + threadIdx.x;
    if (e >= N_EDGES) return;
    int d = ei[N_EDGES + e];
    int pos = atomicAdd(&cursor[d], 1);
    src_s[pos] = ei[e];
    dst_s[pos] = d;
}

// ---------------------------------------------------------------- weight prep (all bf16, transposed [o][k])
__global__ void w2bf_kernel(const float* __restrict__ m2_w, unsigned short* __restrict__ W2T) {
    int idx = blockIdx.x * 256 + threadIdx.x;   // 6*128*128
    int l = idx >> 14;
    int rem = idx & 16383;
    int n = rem >> 7, k = rem & 127;
    W2T[idx] = f2bf(m2_w[l * 16384 + k * HID + n]);
}

// wAB layout: [l][pass(A=0,B=1)][o=128][k=160]; k<128 = f-part, k>=128 = xin-part
__global__ void w1t_kernel(const float* __restrict__ m1_w, unsigned short* __restrict__ wAB) {
    int idx = blockIdx.x * 256 + threadIdx.x;   // 6*2*128*160 = 245760
    int l = idx / (2 * 128 * 160);
    int rem = idx % (2 * 128 * 160);
    int pass = rem / (128 * 160);
    int o = (rem % (128 * 160)) / 160;
    int k = rem % 160;
    const float* M = m1_w + (size_t)l * 284 * 128;
    float v;
    if (k < 128) {
        v = M[(pass ? 128 + k : k) * 128 + o];
    } else {
        int ku = k - 128;
        if (ku < 25) v = M[(256 + ku) * 128 + o];
        else if (ku == 25) v = M[281 * 128 + o];
        else if (ku == 26) v = M[282 * 128 + o];
        else if (ku == 27) v = M[283 * 128 + o];
        else v = 0.0f;
        if (pass) v = (ku <= 25) ? -v : 0.0f;
    }
    wAB[idx] = f2bf(v);
}

__global__ void u1t_kernel(const float* __restrict__ u1_w, unsigned short* __restrict__ U1T) {
    int idx = blockIdx.x * 256 + threadIdx.x;   // 6*128*256
    int l = idx >> 15;
    int o = (idx >> 8) & 127;
    int k = idx & 255;
    U1T[idx] = f2bf(u1_w[(size_t)l * 258 * 128 + k * 128 + o]);
}

__global__ void u2t_kernel(const float* __restrict__ u2_w, unsigned short* __restrict__ U2T) {
    int idx = blockIdx.x * 256 + threadIdx.x;   // 6*128*128
    int l = idx >> 14;
    int o = (idx >> 7) & 127;
    int k = idx & 127;
    U2T[idx] = f2bf(u2_w[(size_t)l * 16384 + k * 128 + o]);
}

// emb weights: we1T[o][32] (rows 28..31 zero), we2T[o][128]
__global__ void wemb_kernel(const float* __restrict__ ew1, const float* __restrict__ ew2,
                            unsigned short* __restrict__ we1T, unsigned short* __restrict__ we2T) {
    int idx = blockIdx.x * 256 + threadIdx.x;   // 4096 + 16384 = 20480
    if (idx < 4096) {
        int o = idx >> 5, k = idx & 31;
        we1T[idx] = f2bf(k < 28 ? ew1[k * HID + o] : 0.0f);
    } else {
        int j = idx - 4096;
        int o = j >> 7, k = j & 127;
        we2T[j] = f2bf(ew2[k * HID + o]);
    }
}

// xin[n][32] = [u(25), pos/16, t/4, v, 0...] bf16
__global__ void xin_kernel(const float* __restrict__ u, const float* __restrict__ xpos,
                           const float* __restrict__ tpos, const float* __restrict__ vars,
                           unsigned short* __restrict__ xin) {
    int idx = blockIdx.x * 256 + threadIdx.x;   // 65536*32
    int n = idx >> 5, k = idx & 31;
    float v;
    if (k < 25) v = u[n * TW + k];
    else if (k == 25) v = xpos[n] * (1.0f / 16.0f);
    else if (k == 26) v = tpos[n] * 0.25f;
    else if (k == 27) v = vars[n];
    else v = 0.0f;
    xin[idx] = f2bf(v);
}

// ---------------------------------------------------------------- abv chunk: one 32-col group (2 cf), 16 AGPR live
__device__ __forceinline__ void abv_chunk(
    const bf16x8 (&afr)[2][5], int nb, int lr, int lk, int colbase,
    const unsigned short* __restrict__ Wp, const float* __restrict__ b1,
    unsigned short* __restrict__ Op)
{
    f32x4 acc[2][2];
    #pragma unroll
    for (int rt = 0; rt < 2; ++rt)
        #pragma unroll
        for (int cf2 = 0; cf2 < 2; ++cf2)
            acc[rt][cf2] = (f32x4){0.0f, 0.0f, 0.0f, 0.0f};
    #pragma unroll
    for (int cf2 = 0; cf2 < 2; ++cf2) {
        const unsigned short* wrow = Wp + (colbase + cf2 * 16 + lr) * 160 + lk * 8;
        #pragma unroll
        for (int ks = 0; ks < 5; ++ks) {
            bf16x8 bfr = *reinterpret_cast<const bf16x8*>(wrow + ks * 32);
            acc[0][cf2] = __builtin_amdgcn_mfma_f32_16x16x32_bf16(afr[0][ks], bfr, acc[0][cf2], 0, 0, 0);
            acc[1][cf2] = __builtin_amdgcn_mfma_f32_16x16x32_bf16(afr[1][ks], bfr, acc[1][cf2], 0, 0, 0);
        }
    }
    #pragma unroll
    for (int cf2 = 0; cf2 < 2; ++cf2) {
        int col = colbase + cf2 * 16 + lr;
        float bb = b1 ? b1[col] : 0.0f;
        #pragma unroll
        for (int rt = 0; rt < 2; ++rt) {
            #pragma unroll
            for (int j = 0; j < 4; ++j) {
                int row = nb + rt * 16 + lk * 4 + j;
                Op[(size_t)row * HID + col] = f2bf_rne(acc[rt][cf2][j] + bb);
            }
        }
    }
}

// ---------------------------------------------------------------- fused emb + layer-0 abv (all MFMA; per-wave 32 rows)
__global__ __launch_bounds__(256) void emb_abv_kernel(
    const unsigned short* __restrict__ xin_bf,
    const unsigned short* __restrict__ we1T, const float* __restrict__ eb1,
    const unsigned short* __restrict__ we2T, const float* __restrict__ eb2,
    const unsigned short* __restrict__ wA, const unsigned short* __restrict__ wB,
    const float* __restrict__ b1,
    unsigned short* __restrict__ f_bf,
    unsigned short* __restrict__ A_bf, unsigned short* __restrict__ Bv_bf)
{
    __shared__ unsigned short q_lds[4 * 32 * HID];   // 32 KB, per-wave 8 KB regions
    const int tid = threadIdx.x;
    const int w = tid >> 6, l = tid & 63;
    const int lr = l & 15, lk = l >> 4;
    const int nb = blockIdx.x * 128 + w * 32;
    char* qbase = reinterpret_cast<char*>(q_lds) + w * 8192;

    bf16x8 xfr[2];
    #pragma unroll
    for (int rt = 0; rt < 2; ++rt)
        xfr[rt] = *reinterpret_cast<const bf16x8*>(xin_bf + (size_t)(nb + rt * 16 + lr) * 32 + lk * 8);

    // GEMM1 (K=32) chunked
    #pragma unroll 1
    for (int cc = 0; cc < 4; ++cc) {
        f32x4 acc1[2][2];
        #pragma unroll
        for (int rt = 0; rt < 2; ++rt)
            #pragma unroll
            for (int cf2 = 0; cf2 < 2; ++cf2)
                acc1[rt][cf2] = (f32x4){0.0f, 0.0f, 0.0f, 0.0f};
        #pragma unroll
        for (int cf2 = 0; cf2 < 2; ++cf2) {
            bf16x8 bfr = *reinterpret_cast<const bf16x8*>(we1T + ((cc * 2 + cf2) * 16 + lr) * 32 + lk * 8);
            acc1[0][cf2] = __builtin_amdgcn_mfma_f32_16x16x32_bf16(xfr[0], bfr, acc1[0][cf2], 0, 0, 0);
            acc1[1][cf2] = __builtin_amdgcn_mfma_f32_16x16x32_bf16(xfr[1], bfr, acc1[1][cf2], 0, 0, 0);
        }
        #pragma unroll
        for (int cf2 = 0; cf2 < 2; ++cf2) {
            int col = (cc * 2 + cf2) * 16 + lr;
            float bb = eb1[col];
            #pragma unroll
            for (int rt = 0; rt < 2; ++rt)
                #pragma unroll
                for (int j = 0; j < 4; ++j) {
                    float qv = swishf(acc1[rt][cf2][j] + bb);
                    int rloc = rt * 16 + lk * 4 + j;
                    *reinterpret_cast<unsigned short*>(qbase + rloc * 256 + ((col * 2) ^ ((rloc & 7) << 4))) = f2bf_rne(qv);
                }
        }
    }

    // GEMM2 (K=128) chunked; f kept in second LDS region
    __shared__ unsigned short f_lds2[4 * 32 * HID];
    char* fbase = reinterpret_cast<char*>(f_lds2) + w * 8192;
    #pragma unroll 1
    for (int cc = 0; cc < 4; ++cc) {
        f32x4 acc2[2][2];
        #pragma unroll
        for (int rt = 0; rt < 2; ++rt)
            #pragma unroll
            for (int cf2 = 0; cf2 < 2; ++cf2)
                acc2[rt][cf2] = (f32x4){0.0f, 0.0f, 0.0f, 0.0f};
        #pragma unroll
        for (int ks = 0; ks < 4; ++ks) {
            bf16x8 afrq[2];
            #pragma unroll
            for (int rt = 0; rt < 2; ++rt) {
                int rloc = rt * 16 + lr;
                afrq[rt] = *reinterpret_cast<const bf16x8*>(qbase + rloc * 256 + ((ks * 64 + lk * 16) ^ ((rloc & 7) << 4)));
            }
            #pragma unroll
            for (int cf2 = 0; cf2 < 2; ++cf2) {
                bf16x8 bfr = *reinterpret_cast<const bf16x8*>(we2T + ((cc * 2 + cf2) * 16 + lr) * HID + ks * 32 + lk * 8);
                acc2[0][cf2] = __builtin_amdgcn_mfma_f32_16x16x32_bf16(afrq[0], bfr, acc2[0][cf2], 0, 0, 0);
                acc2[1][cf2] = __builtin_amdgcn_mfma_f32_16x16x32_bf16(afrq[1], bfr, acc2[1][cf2], 0, 0, 0);
            }
        }
        #pragma unroll
        for (int cf2 = 0; cf2 < 2; ++cf2) {
            int col = (cc * 2 + cf2) * 16 + lr;
            float bb = eb2[col];
            #pragma unroll
            for (int rt = 0; rt < 2; ++rt)
                #pragma unroll
                for (int j = 0; j < 4; ++j) {
                    float fv = swishf(acc2[rt][cf2][j] + bb);
                    unsigned short fb = f2bf_rne(fv);
                    int rloc = rt * 16 + lk * 4 + j;
                    f_bf[(size_t)(nb + rloc) * HID + col] = fb;
                    *reinterpret_cast<unsigned short*>(fbase + rloc * 256 + ((col * 2) ^ ((rloc & 7) << 4))) = fb;
                }
        }
    }

    bf16x8 afr[2][5];
    #pragma unroll
    for (int rt = 0; rt < 2; ++rt) {
        int rloc = rt * 16 + lr;
        #pragma unroll
        for (int ks = 0; ks < 4; ++ks)
            afr[rt][ks] = *reinterpret_cast<const bf16x8*>(fbase + rloc * 256 + ((ks * 64 + lk * 16) ^ ((rloc & 7) << 4)));
        afr[rt][4] = xfr[rt];
    }
    #pragma unroll 1
    for (int cc = 0; cc < 4; ++cc) abv_chunk(afr, nb, lr, lk, cc * 32, wA, b1, A_bf);
    #pragma unroll 1
    for (int cc = 0; cc < 4; ++cc) abv_chunk(afr, nb, lr, lk, cc * 32, wB, nullptr, Bv_bf);
}

// ---------------------------------------------------------------- fused norm + next-layer abv — col-split block (32 rows, grid 2048)
__global__ __launch_bounds__(256) void norm_abv_kernel(
    const unsigned short* __restrict__ h, const int* __restrict__ batch,
    const float* __restrict__ dsum, const float* __restrict__ dsq,
    const float* __restrict__ gcount,
    const unsigned short* __restrict__ xin_bf,
    const unsigned short* __restrict__ wA, const unsigned short* __restrict__ wB,
    const float* __restrict__ b1,
    unsigned short* __restrict__ f_bf,
    unsigned short* __restrict__ A_bf, unsigned short* __restrict__ Bv_bf)
{
    __shared__ unsigned short f_lds[32 * HID];   // 8 KB, shared across waves
    const int tid = threadIdx.x;
    const int w = tid >> 6, l = tid & 63;
    const int lr = l & 15, lk = l >> 4;
    const int nb = blockIdx.x * 32;

    // phase 1: wave w normalizes k-slice ks=w (cols w*32 + lk*8 .. +8) for all 32 rows
    {
        const int ks = w;
        const int c0 = ks * 32 + lk * 8;
        #pragma unroll
        for (int rt = 0; rt < 2; ++rt) {
            int row = nb + rt * 16 + lr;
            int b = batch[row];
            float inv = 1.0f / gcount[b];
            uint4 hv4 = *reinterpret_cast<const uint4*>(h + (size_t)row * HID + c0);
            unsigned int hw[4] = {hv4.x, hv4.y, hv4.z, hv4.w};
            float4 s0 = *reinterpret_cast<const float4*>(dsum + b * HID + c0);
            float4 s1 = *reinterpret_cast<const float4*>(dsum + b * HID + c0 + 4);
            float4 q0 = *reinterpret_cast<const float4*>(dsq + b * HID + c0);
            float4 q1 = *reinterpret_cast<const float4*>(dsq + b * HID + c0 + 4);
            float o[8];
            #pragma unroll
            for (int i = 0; i < 8; ++i) {
                float hx = (i & 1) ? __uint_as_float(hw[i >> 1] & 0xffff0000u)
                                   : __uint_as_float(hw[i >> 1] << 16);
                float sm = (i < 4) ? reinterpret_cast<const float*>(&s0)[i] : reinterpret_cast<const float*>(&s1)[i - 4];
                float sq = (i < 4) ? reinterpret_cast<const float*>(&q0)[i] : reinterpret_cast<const float*>(&q1)[i - 4];
                float mean = sm * inv;
                float var = sq * inv - mean * mean;
                o[i] = (hx - mean) * rsqrtf(var + EPSF);
            }
            uint4 t;
            t.x = cvtpk2bf(o[0], o[1]);
            t.y = cvtpk2bf(o[2], o[3]);
            t.z = cvtpk2bf(o[4], o[5]);
            t.w = cvtpk2bf(o[6], o[7]);
            *reinterpret_cast<uint4*>(f_bf + (size_t)row * HID + c0) = t;
            int rloc = rt * 16 + lr;
            *reinterpret_cast<uint4*>(reinterpret_cast<char*>(f_lds) + rloc * 256 + ((c0 * 2) ^ ((rloc & 7) << 4))) = t;
        }
    }
    __syncthreads();

    // phase 2: each wave computes its 32-col chunk of A and Bv
    bf16x8 afr[2][5];
    #pragma unroll
    for (int rt = 0; rt < 2; ++rt) {
        int rloc = rt * 16 + lr;
        #pragma unroll
        for (int ks = 0; ks < 4; ++ks)
            afr[rt][ks] = *reinterpret_cast<const bf16x8*>(
                reinterpret_cast<const char*>(f_lds) + rloc * 256 + ((ks * 64 + lk * 16) ^ ((rloc & 7) << 4)));
        afr[rt][4] = *reinterpret_cast<const bf16x8*>(xin_bf + (size_t)(nb + rt * 16 + lr) * 32 + lk * 8);
    }
    abv_chunk(afr, nb, lr, lk, w * 32, wA, b1, A_bf);
    abv_chunk(afr, nb, lr, lk, w * 32, wB, nullptr, Bv_bf);
}

// ---------------------------------------------------------------- fused edge kernel: LDS-free direct fragment gather, chunked
__global__ __launch_bounds__(256) void edge_mfma_kernel(
    const int* __restrict__ src_s, const int* __restrict__ dst_s,
    const unsigned short* __restrict__ A_bf, const unsigned short* __restrict__ Bv_bf,
    const unsigned short* __restrict__ W2T, const float* __restrict__ b2,
    float* __restrict__ agg)
{
    const int tid = threadIdx.x;
    const int w = tid >> 6, l = tid & 63;
    const int lr = l & 15, lk = l >> 4;
    const int e0 = blockIdx.x * TILE_E + w * 32;

    bf16x8 afr[2][4];
    #pragma unroll
    for (int rt = 0; rt < 2; ++rt) {
        int e = e0 + ((lr >> 2) << 3) + rt * 4 + (lr & 3);
        int dn = dst_s[e], sn = src_s[e];
        const unsigned short* ap = A_bf + (size_t)dn * HID + lk * 8;
        const unsigned short* bp = Bv_bf + (size_t)sn * HID + lk * 8;
        #pragma unroll
        for (int ks = 0; ks < 4; ++ks) {
            uint4 av = *reinterpret_cast<const uint4*>(ap + ks * 32);
            uint4 bv = *reinterpret_cast<const uint4*>(bp + ks * 32);
            auto proc = [](unsigned int aw, unsigned int bw) -> unsigned int {
                float a0 = __uint_as_float(aw << 16), a1 = __uint_as_float(aw & 0xffff0000u);
                float b0 = __uint_as_float(bw << 16), b1 = __uint_as_float(bw & 0xffff0000u);
                return cvtpk2bf(swishf(a0 + b0), swishf(a1 + b1));
            };
            union { bf16x8 v; unsigned int u[4]; } t;
            t.u[0] = proc(av.x, bv.x);
            t.u[1] = proc(av.y, bv.y);
            t.u[2] = proc(av.z, bv.z);
            t.u[3] = proc(av.w, bv.w);
            afr[rt][ks] = t.v;
        }
    }

    const int ebase = e0 + lk * 8;
    int4 dA4 = *reinterpret_cast<const int4*>(dst_s + ebase);
    int4 dB4 = *reinterpret_cast<const int4*>(dst_s + ebase + 4);
    int d[8] = {dA4.x, dA4.y, dA4.z, dA4.w, dB4.x, dB4.y, dB4.z, dB4.w};
    bool sm[7];
    int roff[8];
    #pragma unroll
    for (int m = 0; m < 7; ++m) sm[m] = (d[m + 1] == d[m]);
    #pragma unroll
    for (int m = 0; m < 8; ++m) roff[m] = d[m] * HID;

    #pragma unroll 1
    for (int cc = 0; cc < 4; ++cc) {
        f32x4 acc[2][2];
        #pragma unroll
        for (int rt = 0; rt < 2; ++rt)
            #pragma unroll
            for (int cf2 = 0; cf2 < 2; ++cf2)
                acc[rt][cf2] = (f32x4){0.0f, 0.0f, 0.0f, 0.0f};
        #pragma unroll
        for (int cf2 = 0; cf2 < 2; ++cf2) {
            const unsigned short* wrow = W2T + ((cc * 2 + cf2) * 16 + lr) * HID + lk * 8;
            #pragma unroll
            for (int ks = 0; ks < 4; ++ks) {
                bf16x8 bfr = *reinterpret_cast<const bf16x8*>(wrow + ks * 32);
                acc[0][cf2] = __builtin_amdgcn_mfma_f32_16x16x32_bf16(afr[0][ks], bfr, acc[0][cf2], 0, 0, 0);
                acc[1][cf2] = __builtin_amdgcn_mfma_f32_16x16x32_bf16(afr[1][ks], bfr, acc[1][cf2], 0, 0, 0);
            }
        }
        #pragma unroll
        for (int cf2 = 0; cf2 < 2; ++cf2) {
            int col = (cc * 2 + cf2) * 16 + lr;
            float bias = b2[col];
            float v[8];
            #pragma unroll
            for (int m = 0; m < 8; ++m) v[m] = swishf(acc[m >> 2][cf2][m & 3] + bias);
            float run = v[0];
            #pragma unroll
            for (int m = 1; m < 8; ++m) {
                if (sm[m - 1]) run += v[m];
                else { atomicAdd(&agg[(size_t)roff[m - 1] + col], run); run = v[m]; }
            }
            atomicAdd(&agg[(size_t)roff[7] + col], run);
        }
    }
}

// ---------------------------------------------------------------- update — col-split block (32 rows, grid 2048)
// zeroes its own agg rows after GEMM1 (replaces per-layer memset)
__global__ __launch_bounds__(256) void update_mfma_kernel(
    const unsigned short* __restrict__ f_bf, float* __restrict__ agg,
    const int* __restrict__ cnt,
    const float* __restrict__ tpos, const float* __restrict__ vars,
    const int* __restrict__ batch,
    const unsigned short* __restrict__ U1T, const float* __restrict__ u1tv,
    const float* __restrict__ b1, const unsigned short* __restrict__ U2T,
    const float* __restrict__ b2, unsigned short* __restrict__ h,
    float* __restrict__ dsum, float* __restrict__ dsq)
{
    __shared__ unsigned short q_lds[32 * HID];   // 8 KB, shared across waves
    const int tid = threadIdx.x;
    const int w = tid >> 6, l = tid & 63;
    const int lr = l & 15, lk = l >> 4;
    const int nb = blockIdx.x * 32;

    float invd[2];
    #pragma unroll
    for (int rt = 0; rt < 2; ++rt) {
        int c = cnt[nb + rt * 16 + lr];
        invd[rt] = 1.0f / (float)(c > 0 ? c : 1);
    }
    float tn[2][4], vn[2][4];
    #pragma unroll
    for (int rt = 0; rt < 2; ++rt)
        #pragma unroll
        for (int j = 0; j < 4; ++j) {
            int row = nb + rt * 16 + lk * 4 + j;
            tn[rt][j] = tpos[row] * 0.25f;
            vn[rt][j] = vars[row];
        }

    // GEMM1 (K=256): wave w computes cols w*32..+31
    {
        f32x4 acc[2][2];
        #pragma unroll
        for (int rt = 0; rt < 2; ++rt)
            #pragma unroll
            for (int cf2 = 0; cf2 < 2; ++cf2)
                acc[rt][cf2] = (f32x4){0.0f, 0.0f, 0.0f, 0.0f};
        #pragma unroll
        for (int ks = 0; ks < 8; ++ks) {
            bf16x8 afr[2];
            #pragma unroll
            for (int rt = 0; rt < 2; ++rt) {
                int row = nb + rt * 16 + lr;
                if (ks < 4) {
                    afr[rt] = *reinterpret_cast<const bf16x8*>(f_bf + (size_t)row * HID + ks * 32 + lk * 8);
                } else {
                    const float* ap = agg + (size_t)row * HID + (ks - 4) * 32 + lk * 8;
                    float4 a0 = *reinterpret_cast<const float4*>(ap);
                    float4 a1 = *reinterpret_cast<const float4*>(ap + 4);
                    float iv = invd[rt];
                    union { bf16x8 v; unsigned int u[4]; } t;
                    t.u[0] = cvtpk2bf(a0.x * iv, a0.y * iv);
                    t.u[1] = cvtpk2bf(a0.z * iv, a0.w * iv);
                    t.u[2] = cvtpk2bf(a1.x * iv, a1.y * iv);
                    t.u[3] = cvtpk2bf(a1.z * iv, a1.w * iv);
                    afr[rt] = t.v;
                }
            }
            #pragma unroll
            for (int cf2 = 0; cf2 < 2; ++cf2) {
                bf16x8 bfr = *reinterpret_cast<const bf16x8*>(U1T + ((w * 2 + cf2) * 16 + lr) * 256 + ks * 32 + lk * 8);
                acc[0][cf2] = __builtin_amdgcn_mfma_f32_16x16x32_bf16(afr[0], bfr, acc[0][cf2], 0, 0, 0);
                acc[1][cf2] = __builtin_amdgcn_mfma_f32_16x16x32_bf16(afr[1], bfr, acc[1][cf2], 0, 0, 0);
            }
        }
        // epilogue 1: tv + bias + swish -> shared q_lds (swizzled)
        #pragma unroll
        for (int cf2 = 0; cf2 < 2; ++cf2) {
            int col = w * 32 + cf2 * 16 + lr;
            float bb = b1[col], wt = u1tv[col], wv = u1tv[HID + col];
            #pragma unroll
            for (int rt = 0; rt < 2; ++rt)
                #pragma unroll
                for (int j = 0; j < 4; ++j) {
                    float qv = swishf(acc[rt][cf2][j] + bb + tn[rt][j] * wt + vn[rt][j] * wv);
                    int rloc = rt * 16 + lk * 4 + j;
                    *reinterpret_cast<unsigned short*>(reinterpret_cast<char*>(q_lds) + rloc * 256 + ((col * 2) ^ ((rloc & 7) << 4))) = f2bf_rne(qv);
                }
        }
    }
    __syncthreads();

    // zero own agg rows for next layer's edge accumulation (replaces per-layer memset);
    // safe: all waves' GEMM1 agg reads completed before the barrier above
    {
        #pragma unroll
        for (int i = 0; i < 4; ++i) {
            int q = tid + i * 256;
            int r = q >> 5, cb = q & 31;
            float4 z = {0.0f, 0.0f, 0.0f, 0.0f};
            *reinterpret_cast<float4*>(agg + (size_t)(nb + r) * HID + cb * 4) = z;
        }
    }

    // GEMM2 (K=128): wave w computes cols w*32..+31
    const int bfirst = batch[nb];
    const bool uni = (bfirst == batch[nb + 31]);
    {
        f32x4 acc2[2][2];
        #pragma unroll
        for (int rt = 0; rt < 2; ++rt)
            #pragma unroll
            for (int cf2 = 0; cf2 < 2; ++cf2)
                acc2[rt][cf2] = (f32x4){0.0f, 0.0f, 0.0f, 0.0f};
        #pragma unroll
        for (int ks = 0; ks < 4; ++ks) {
            bf16x8 afr[2];
            #pragma unroll
            for (int rt = 0; rt < 2; ++rt) {
                int rloc = rt * 16 + lr;
                afr[rt] = *reinterpret_cast<const bf16x8*>(
                    reinterpret_cast<const char*>(q_lds) + rloc * 256 + ((ks * 64 + lk * 16) ^ ((rloc & 7) << 4)));
            }
            #pragma unroll
            for (int cf2 = 0; cf2 < 2; ++cf2) {
                bf16x8 bfr = *reinterpret_cast<const bf16x8*>(U2T + ((w * 2 + cf2) * 16 + lr) * HID + ks * 32 + lk * 8);
                acc2[0][cf2] = __builtin_amdgcn_mfma_f32_16x16x32_bf16(afr[0], bfr, acc2[0][cf2], 0, 0, 0);
                acc2[1][cf2] = __builtin_amdgcn_mfma_f32_16x16x32_bf16(afr[1], bfr, acc2[1][cf2], 0, 0, 0);
            }
        }
        // epilogue 2: residual + h write + stats
        #pragma unroll
        for (int cf2 = 0; cf2 < 2; ++cf2) {
            int col = w * 32 + cf2 * 16 + lr;
            float bb = b2[col];
            float s = 0.0f, s2 = 0.0f;
            #pragma unroll
            for (int rt = 0; rt < 2; ++rt)
                #pragma unroll
                for (int j = 0; j < 4; ++j) {
                    int row = nb + rt * 16 + lk * 4 + j;
                    float fres = bf2f(f_bf[(size_t)row * HID + col]);
                    float hv = fres + swishf(acc2[rt][cf2][j] + bb);
                    unsigned short hb = f2bf_rne(hv);
                    h[(size_t)row * HID + col] = hb;
                    float hvr = bf2f(hb);
                    if (uni) { s += hvr; s2 += hvr * hvr; }
                    else {
                        int b = batch[row];
                        atomicAdd(&dsum[b * HID + col], hvr);
                        atomicAdd(&dsq[b * HID + col], hvr * hvr);
                    }
                }
            if (uni) {
                s += __shfl_xor(s, 16); s += __shfl_xor(s, 32);
                s2 += __shfl_xor(s2, 16); s2 += __shfl_xor(s2, 32);
                if (lk == 0) {
                    atomicAdd(&dsum[bfirst * HID + col], s);
                    atomicAdd(&dsq[bfirst * HID + col], s2);
                }
            }
        }
    }
}

// ---------------------------------------------------------------- conv head with fused final instance-norm
__global__ __launch_bounds__(256) void head_kernel(
    const unsigned short* __restrict__ h, const int* __restrict__ batch,
    const float* __restrict__ dsum, const float* __restrict__ dsq,
    const float* __restrict__ gcount,
    const float* __restrict__ u,
    const float* __restrict__ c1w, const float* __restrict__ c1b,
    const float* __restrict__ c2w, const float* __restrict__ c2b,
    float* __restrict__ out)
{
    __shared__ float fs[16][HID];
    __shared__ float y1[16][8][40];
    const int tid = threadIdx.x;
    const int n0 = blockIdx.x * 16;
    {
        int node = tid >> 4, cb = tid & 15;
        int n = n0 + node;
        int b = batch[n];
        float inv = 1.0f / gcount[b];
        int c0 = cb * 8;
        uint4 v = *reinterpret_cast<const uint4*>(h + (size_t)n * HID + c0);
        unsigned int wv[4] = {v.x, v.y, v.z, v.w};
        #pragma unroll
        for (int i = 0; i < 8; ++i) {
            float hx = (i & 1) ? __uint_as_float(wv[i >> 1] & 0xffff0000u)
                               : __uint_as_float(wv[i >> 1] << 16);
            float mean = dsum[b * HID + c0 + i] * inv;
            float var = dsq[b * HID + c0 + i] * inv - mean * mean;
            fs[node][c0 + i] = (hx - mean) * rsqrtf(var + EPSF);
        }
    }
    __syncthreads();
    {
        const int node = tid >> 4;
        const int rem = tid & 15;
        const int o = rem >> 1;
        const int ph = rem & 1;
        const float cb = c1b[o];
        float wk[16];
        #pragma unroll
        for (int k = 0; k < 16; ++k) wk[k] = c1w[o * 16 + k];
        for (int p = ph * 19; p < ph * 19 + 19; ++p) {
            float acc = cb;
            #pragma unroll
            for (int k = 0; k < 16; ++k) acc += fs[node][p * 3 + k] * wk[k];
            y1[node][o][p] = swishf(acc);
        }
    }
    __syncthreads();
    const float cb2 = c2b[0];
    #pragma unroll
    for (int pass = 0; pass < 2; ++pass) {
        int unit = tid + pass * 256;
        if (unit < 16 * TW) {
            int node = unit / TW, t = unit % TW;
            float acc = cb2;
            #pragma unroll
            for (int o = 0; o < 8; ++o)
                #pragma unroll
                for (int k = 0; k < 14; ++k)
                    acc += y1[node][o][t + k] * c2w[o * 14 + k];
            int n = n0 + node;
            out[n * TW + t] = u[n * TW + (TW - 1)] + (0.016f * (float)(t + 1)) * acc;
        }
    }
}

// ---------------------------------------------------------------- launch
extern "C" void kernel_launch(void* const* d_in, const int* in_sizes, int n_in,
                              void* d_out, int out_size, void* d_ws, size_t ws_size,
                              hipStream_t stream)
{
    (void)in_sizes; (void)n_in; (void)out_size; (void)ws_size;
    const float* u      = (const float*)d_in[0];
    const float* xpos   = (const float*)d_in[1];
    const float* tpos   = (const float*)d_in[2];
    const float* vars   = (const float*)d_in[3];
    const int*   ei     = (const int*)d_in[4];
    const int*   batch  = (const int*)d_in[5];
    const float* emb_w1 = (const float*)d_in[6];
    const float* emb_b1 = (const float*)d_in[7];
    const float* emb_w2 = (const float*)d_in[8];
    const float* emb_b2 = (const float*)d_in[9];
    const float* m1_w   = (const float*)d_in[10];
    const float* m1_b   = (const float*)d_in[11];
    const float* m2_w   = (const float*)d_in[12];
    const float* m2_b   = (const float*)d_in[13];
    const float* u1_w   = (const float*)d_in[14];
    const float* u1_b   = (const float*)d_in[15];
    const float* u2_w   = (const float*)d_in[16];
    const float* u2_b   = (const float*)d_in[17];
    const float* c1w    = (const float*)d_in[18];
    const float* c1b    = (const float*)d_in[19];
    const float* c2w    = (const float*)d_in[20];
    const float* c2b    = (const float*)d_in[21];
    float* out = (float*)d_out;

    char* ws = (char*)d_ws;
    const size_t fbytes = (size_t)N_NODES * HID * sizeof(float);
    float* agg    = (float*)(ws);
    char*  p      = ws + fbytes;
    unsigned short* h_bf   = (unsigned short*)p;  p += (size_t)N_NODES * HID * 2;
    unsigned short* A_bf   = (unsigned short*)p;  p += (size_t)N_NODES * HID * 2;
    unsigned short* Bv_bf  = (unsigned short*)p;  p += (size_t)N_NODES * HID * 2;
    unsigned short* f_bf   = (unsigned short*)p;  p += (size_t)N_NODES * HID * 2;
    unsigned short* xin_bf = (unsigned short*)p;  p += (size_t)N_NODES * 32 * 2;
    int* cnt      = (int*)p;               p += (size_t)N_NODES * 4;
    int* cursor   = (int*)p;               p += (size_t)N_NODES * 4;
    int* src_s    = (int*)p;               p += (size_t)N_EDGES * 4;
    int* dst_s    = (int*)p;               p += (size_t)N_EDGES * 4;
    int* bsum     = (int*)p;               p += 256 * 4;
    int* bpref    = (int*)p;               p += 256 * 4;
    float* dsumL  = (float*)p;             p += (size_t)LAYERS * BGRAPH * HID * 4;
    float* dsqL   = (float*)p;             p += (size_t)LAYERS * BGRAPH * HID * 4;
    float* gcount = (float*)p;             p += BGRAPH * 4;
    unsigned short* W2T  = (unsigned short*)p;  p += (size_t)LAYERS * HID * HID * 2;
    unsigned short* wAB  = (unsigned short*)p;  p += (size_t)LAYERS * 2 * 128 * 160 * 2;
    unsigned short* U1T  = (unsigned short*)p;  p += (size_t)LAYERS * 128 * 256 * 2;
    unsigned short* U2T  = (unsigned short*)p;  p += (size_t)LAYERS * 128 * 128 * 2;
    unsigned short* we1T = (unsigned short*)p;  p += 128 * 32 * 2;
    unsigned short* we2T = (unsigned short*)p;  p += 128 * 128 * 2;

    // CSR build
    hipMemsetAsync(cnt, 0, (size_t)N_NODES * 4, stream);
    count_kernel<<<N_EDGES / 256, 256, 0, stream>>>(ei, cnt);
    block_sum_kernel<<<N_NODES / 256, 256, 0, stream>>>(cnt, bsum);
    scan_bsum_kernel<<<1, 256, 0, stream>>>(bsum, bpref);
    offsets_kernel<<<N_NODES / 256, 256, 0, stream>>>(cnt, bpref, cursor);
    scatter_kernel<<<N_EDGES / 256, 256, 0, stream>>>(ei, cursor, src_s, dst_s);

    // weight / input prep
    w2bf_kernel<<<LAYERS * HID * HID / 256, 256, 0, stream>>>(m2_w, W2T);
    w1t_kernel<<<LAYERS * 2 * 128 * 160 / 256, 256, 0, stream>>>(m1_w, wAB);
    u1t_kernel<<<LAYERS * 128 * 256 / 256, 256, 0, stream>>>(u1_w, U1T);
    u2t_kernel<<<LAYERS * 128 * 128 / 256, 256, 0, stream>>>(u2_w, U2T);
    wemb_kernel<<<80, 256, 0, stream>>>(emb_w1, emb_w2, we1T, we2T);
    xin_kernel<<<N_NODES * 32 / 256, 256, 0, stream>>>(u, xpos, tpos, vars, xin_bf);
    gcount_kernel<<<1, 64, 0, stream>>>(batch, gcount);
    hipMemsetAsync(dsumL, 0, (size_t)2 * LAYERS * BGRAPH * HID * 4, stream);
    hipMemsetAsync(agg, 0, fbytes, stream);   // once; update kernels re-zero per layer

    // fused emb + layer-0 abv
    emb_abv_kernel<<<N_NODES / 128, 256, 0, stream>>>(
        xin_bf, we1T, emb_b1, we2T, emb_b2,
        wAB, wAB + 128 * 160, m1_b, f_bf, A_bf, Bv_bf);

    for (int l = 0; l < LAYERS; ++l) {
        edge_mfma_kernel<<<N_EDGES / TILE_E, 256, 0, stream>>>(
            src_s, dst_s, A_bf, Bv_bf, W2T + (size_t)l * HID * HID,
            m2_b + (size_t)l * HID, agg);
        update_mfma_kernel<<<N_NODES / 32, 256, 0, stream>>>(
            f_bf, agg, cnt, tpos, vars, batch,
            U1T + (size_t)l * 128 * 256,
            u1_w + (size_t)l * 258 * 128 + 256 * 128,
            u1_b + (size_t)l * HID,
            U2T + (size_t)l * 128 * 128,
            u2_b + (size_t)l * HID, h_bf,
            dsumL + (size_t)l * BGRAPH * HID, dsqL + (size_t)l * BGRAPH * HID);
        if (l < LAYERS - 1) {
            norm_abv_kernel<<<N_NODES / 32, 256, 0, stream>>>(
                h_bf, batch, dsumL + (size_t)l * BGRAPH * HID, dsqL + (size_t)l * BGRAPH * HID,
                gcount, xin_bf,
                wAB + (size_t)(l + 1) * 2 * 128 * 160,
                wAB + (size_t)(l + 1) * 2 * 128 * 160 + 128 * 160,
                m1_b + (size_t)(l + 1) * HID,
                f_bf, A_bf, Bv_bf);
        }
    }
    head_kernel<<<N_NODES / 16, 256, 0, stream>>>(
        h_bf, batch, dsumL + (size_t)(LAYERS - 1) * BGRAPH * HID,
        dsqL + (size_t)(LAYERS - 1) * BGRAPH * HID, gcount,
        u, c1w, c1b, c2w, c2b, out);
}